// Round 6
// baseline (179.696 us; speedup 1.0000x reference)
//
#include <hip/hip_runtime.h>

// Depthwise causal conv1d, k=3.
// x: (8, 768, 4096) fp32, weight: (768, 1, 3) fp32, y: (8, 768, 4096) fp32.
// y[n,c,t] = w[c,0]*x[t-2] + w[c,1]*x[t-1] + w[c,2]*x[t], zeros left of t=0.
//
// v7: flat grid-stride structure == the 6.3 TB/s copy ubench + conv math.
// Ladder: v1 ~54us / v5 ~56us / v6 59.5us all used short-lived one-shot
// blocks (setup -> few loads -> wait -> store -> exit); counters show
// VALUBusy 3.6%, occupancy 60%, HBM 2.5 TB/s: nothing busy => the cap is
// the bursty per-block lifecycle, not bytes (traffic already minimal:
// FETCH 49 MB + WRITE 98 MB). v7 uses 2048 resident blocks x 12-iteration
// grid-stride, steady-state load issue like the fill/copy kernels.
//
// Correctness structure per float4 i:
//   m1 = x[4i-1], m2 = x[4i-2] via __shfl_up from lane l-1; wave-lead lanes
//   take them from an unconditional clamped float2 load (same cache lines);
//   row starts (i % 1024 == 0) zero the history (causal edge).
// A wave spans 64 consecutive float4 = 256 floats; 4096 % 256 == 0 so a wave
// never crosses a row boundary -> row is wave-uniform -> readfirstlane makes
// the weight fetch a scalar SMEM load.

#define CONV_L   4096
#define CONV_C   768
#define N_F4     (8 * CONV_C * CONV_L / 4)   // 6,291,456 float4s
#define THREADS  256
#define BLOCKS   2048
#define STRIDE   (BLOCKS * THREADS)          // 524,288 float4 per sweep
#define ITERS    (N_F4 / STRIDE)             // 12, exact

__global__ __launch_bounds__(THREADS) void dwconv1d_k3_flat(
    const float* __restrict__ x,
    const float* __restrict__ w,
    float* __restrict__ y)
{
    const int  tid  = blockIdx.x * THREADS + threadIdx.x;
    const bool lead = (threadIdx.x & 63) == 0;

#pragma unroll 4
    for (int it = 0; it < ITERS; ++it) {
        const int i = tid + it * STRIDE;          // global float4 index
        const float4 cur = ((const float4*)x)[i];

        // Wave-uniform row -> scalar weight loads.
        const int row = i >> 10;                  // 1024 float4 per row
        const int c   = __builtin_amdgcn_readfirstlane(row) % CONV_C;
        const float w0 = w[c * 3 + 0];
        const float w1 = w[c * 3 + 1];
        const float w2 = w[c * 3 + 2];

        // History x[4i-2], x[4i-1]: issued unconditionally (clamped at i==0),
        // lines are the ones neighboring lanes load anyway -> L1 hits.
        const size_t f = ((size_t)i << 2);
        const float2 h = *(const float2*)(x + (f ? f - 2 : 0));

        float m1 = __shfl_up(cur.w, 1);           // x[4i-1] from lane l-1
        float m2 = __shfl_up(cur.z, 1);           // x[4i-2]
        if (lead)            { m2 = h.x;  m1 = h.y;  }   // wave boundary
        if ((i & 1023) == 0) { m2 = 0.0f; m1 = 0.0f; }   // causal row edge

        float4 o;
        o.x = w0 * m2    + w1 * m1    + w2 * cur.x;
        o.y = w0 * m1    + w1 * cur.x + w2 * cur.y;
        o.z = w0 * cur.x + w1 * cur.y + w2 * cur.z;
        o.w = w0 * cur.y + w1 * cur.z + w2 * cur.w;

        ((float4*)y)[i] = o;
    }
}

extern "C" void kernel_launch(void* const* d_in, const int* in_sizes, int n_in,
                              void* d_out, int out_size, void* d_ws, size_t ws_size,
                              hipStream_t stream)
{
    const float* x = (const float*)d_in[0];
    const float* w = (const float*)d_in[1];
    float* y = (float*)d_out;
    (void)out_size;

    dwconv1d_k3_flat<<<BLOCKS, THREADS, 0, stream>>>(x, w, y);
}

// Round 7
// 174.245 us; speedup vs baseline: 1.0313x; 1.0313x over previous
//
#include <hip/hip_runtime.h>

// Depthwise causal conv1d, k=3.
// x: (8, 768, 4096) fp32, weight: (768, 1, 3) fp32, y: (8, 768, 4096) fp32.
// y[n,c,t] = w[c,0]*x[t-2] + w[c,1]*x[t-1] + w[c,2]*x[t], zeros left of t=0.
//
// v8: kill the load->shfl dependency and PIN the load schedule.
// Evidence trail: v5/v6 VGPR_Count=16, v7=32 -- too small to hold the 4
// float4s each version nominally keeps in flight => the compiler sank every
// load to just before its use (the __shfl_up right after each load forces a
// vmcnt wait and makes sinking look free). Per-thread MLP was ~1 load, and
// all structures converged to ~2.5 TB/s, latency-bound, VALUBusy <6%.
// Fix: (a) no shfl at all -- history comes from an unconditional float2 load
// (same cache lines as neighbors' float4s, L1-hot); (b) all 8 loads issued
// back-to-back, then __builtin_amdgcn_sched_barrier(0) so they cannot be
// sunk; uses follow. Only lane t==0 segment 0 needs the causal edge: clamped
// address + value select (no divergent load).
// Structure otherwise = v6: one block per row, weights loaded once
// (block-uniform c -> scalar loads), thread t owns float4 {t,t+256,t+512,
// t+768}, every memory instruction lane-contiguous, plain stores.

#define CONV_L 4096
#define CONV_C 768

__global__ __launch_bounds__(256) void dwconv1d_k3_pin(
    const float* __restrict__ x,
    const float* __restrict__ w,
    float* __restrict__ y)
{
    const int row = blockIdx.x;          // 0..6143, block-uniform
    const int c   = row % CONV_C;        // uniform -> scalar weight loads

    const float w0 = w[c * 3 + 0];
    const float w1 = w[c * 3 + 1];
    const float w2 = w[c * 3 + 2];

    const float* xrow = x + (size_t)row * CONV_L;
    float*       yrow = y + (size_t)row * CONV_L;

    const int t = threadIdx.x;           // float4 indices t + 256*j, j=0..3
    const float4* xin = (const float4*)xrow;

    // ---- 8 loads, all issued before any use ----
    const float4 c0 = xin[t      ];
    const float4 c1 = xin[t + 256];
    const float4 c2 = xin[t + 512];
    const float4 c3 = xin[t + 768];
    // History floats x[4p-2], x[4p-1] for each segment start p. For t==0
    // segment 0 the address is clamped to the row start (values replaced
    // below); everything else is a plain interior load.
    const float2 h0 = *(const float2*)(xrow + (t ? ((t      ) << 2) - 2 : 0));
    const float2 h1 = *(const float2*)(xrow + (((t + 256) << 2) - 2));
    const float2 h2 = *(const float2*)(xrow + (((t + 512) << 2) - 2));
    const float2 h3 = *(const float2*)(xrow + (((t + 768) << 2) - 2));
    __builtin_amdgcn_sched_barrier(0);   // loads may not be sunk past here

    const bool edge = (t == 0);          // causal left edge of the row
    const float m2_0 = edge ? 0.0f : h0.x;
    const float m1_0 = edge ? 0.0f : h0.y;

    float4* yout = (float4*)yrow;
    float4 o;

#define CONV_SEG(cc, m1, m2, off)                      \
    o.x = w0 * (m2)   + w1 * (m1)   + w2 * (cc).x;     \
    o.y = w0 * (m1)   + w1 * (cc).x + w2 * (cc).y;     \
    o.z = w0 * (cc).x + w1 * (cc).y + w2 * (cc).z;     \
    o.w = w0 * (cc).y + w1 * (cc).z + w2 * (cc).w;     \
    yout[t + (off)] = o;

    CONV_SEG(c0, m1_0, m2_0, 0)
    CONV_SEG(c1, h1.y, h1.x, 256)
    CONV_SEG(c2, h2.y, h2.x, 512)
    CONV_SEG(c3, h3.y, h3.x, 768)
#undef CONV_SEG
}

extern "C" void kernel_launch(void* const* d_in, const int* in_sizes, int n_in,
                              void* d_out, int out_size, void* d_ws, size_t ws_size,
                              hipStream_t stream)
{
    const float* x = (const float*)d_in[0];
    const float* w = (const float*)d_in[1];
    float* y = (float*)d_out;

    const int rows = out_size / CONV_L;   // out_size is ELEMENTS: 8*768 = 6144
    dwconv1d_k3_pin<<<rows, 256, 0, stream>>>(x, w, y);
}